// Round 1
// baseline (309.139 us; speedup 1.0000x reference)
//
#include <hip/hip_runtime.h>
#include <hip/hip_bf16.h>
#include <stdint.h>

// Problem constants
constexpr int NB = 8;     // batch
constexpr int NS = 1024;  // seq
constexpr int ND = 1024;  // model dim
constexpr int NH = 16;    // heads
constexpr int NDK = 64;   // head dim

typedef __bf16 bf16_t;
typedef __attribute__((ext_vector_type(8))) __bf16 bf16x8;
typedef __attribute__((ext_vector_type(4))) __bf16 bf16x4;
typedef __attribute__((ext_vector_type(4))) float f32x4;

#define GLL16(g, s) __builtin_amdgcn_global_load_lds( \
    (const __attribute__((address_space(1))) void*)(g), \
    (__attribute__((address_space(3))) void*)(s), 16, 0, 0)

// ---------------- fp32 -> bf16 convert ----------------
__global__ __launch_bounds__(256) void cvt_kernel(const float* __restrict__ src,
                                                  bf16_t* __restrict__ dst, long n) {
  long i0 = (long)(blockIdx.x * blockDim.x + threadIdx.x) * 4;
  long step = (long)gridDim.x * blockDim.x * 4;
  for (long i = i0; i < n; i += step) {
    float4 f = *(const float4*)(src + i);
    bf16x4 o;
    o[0] = (bf16_t)f.x; o[1] = (bf16_t)f.y; o[2] = (bf16_t)f.z; o[3] = (bf16_t)f.w;
    *(bf16x4*)(dst + i) = o;
  }
}

// ---------------- GEMM: C[M,N] = A[M,K] @ W[N,K]^T + bias ----------------
// 128x128 tile, 4 waves (2x2 of 64x64), BK=32, mfma 16x16x32 bf16.
template<bool OUT_F32>
__global__ __launch_bounds__(256) void gemm_bt(const bf16_t* __restrict__ A,
                                               const bf16_t* __restrict__ W,
                                               const float* __restrict__ bias,
                                               void* __restrict__ Cout,
                                               int M, int N, int K) {
  __shared__ bf16_t As[128 * 32];
  __shared__ bf16_t Bs[128 * 32];
  const int tid = threadIdx.x;
  const int l = tid & 63, w = tid >> 6;
  const int wr = w >> 1, wc = w & 1;
  const int g = l >> 4, r = l & 15;
  const int m0 = blockIdx.y * 128, n0 = blockIdx.x * 128;

  f32x4 acc[4][4] = {};

  for (int k0 = 0; k0 < K; k0 += 32) {
#pragma unroll
    for (int it = 0; it < 2; ++it) {
      int idx = it * 256 + tid;        // chunk 0..511 (16B each)
      int row = idx >> 2, cg = idx & 3;
      GLL16(A + (size_t)(m0 + row) * K + (k0 + cg * 8),
            As + (size_t)(it * 256 + w * 64) * 8);
      GLL16(W + (size_t)(n0 + row) * K + (k0 + cg * 8),
            Bs + (size_t)(it * 256 + w * 64) * 8);
    }
    __syncthreads();
    bf16x8 af[4], bfr[4];
#pragma unroll
    for (int m = 0; m < 4; ++m)
      af[m] = *(const bf16x8*)(As + (wr * 64 + m * 16 + r) * 32 + g * 8);
#pragma unroll
    for (int n = 0; n < 4; ++n)
      bfr[n] = *(const bf16x8*)(Bs + (wc * 64 + n * 16 + r) * 32 + g * 8);
#pragma unroll
    for (int m = 0; m < 4; ++m)
#pragma unroll
      for (int n = 0; n < 4; ++n)
        acc[m][n] = __builtin_amdgcn_mfma_f32_16x16x32_bf16(af[m], bfr[n], acc[m][n], 0, 0, 0);
    __syncthreads();
  }

#pragma unroll
  for (int n = 0; n < 4; ++n) {
    int col = n0 + wc * 64 + n * 16 + r;
    float bv = bias[col];
#pragma unroll
    for (int m = 0; m < 4; ++m) {
      int row0 = m0 + wr * 64 + m * 16 + g * 4;
#pragma unroll
      for (int j = 0; j < 4; ++j) {
        float vv = acc[m][n][j] + bv;
        if (OUT_F32)
          ((float*)Cout)[(size_t)(row0 + j) * N + col] = vv;
        else
          ((bf16_t*)Cout)[(size_t)(row0 + j) * N + col] = (bf16_t)vv;
      }
    }
  }
}

// ---------------- causal flash attention ----------------
// grid (S/64, H, B), 256 threads. Wave w: q rows [qt*64+w*16, +16).
// K tile [64 keys][64 dk] in LDS, XOR-swizzled, staged via global_load_lds with
// pre-swizzled global source. V tile transposed [64 dk][64 key], XOR-swizzled,
// reg-staged. P round-trips through swizzled per-wave LDS to reach A-layout.
__global__ __launch_bounds__(256) void attn_kernel(const bf16_t* __restrict__ Q1,
                                                   const bf16_t* __restrict__ K1,
                                                   const bf16_t* __restrict__ V1,
                                                   bf16_t* __restrict__ attn) {
  const int qt = blockIdx.x, h = blockIdx.y, b = blockIdx.z;
  const int tid = threadIdx.x;
  const int l = tid & 63, w = tid >> 6;
  const int g = l >> 4, r = l & 15;

  __shared__ bf16_t Kt[64 * 64];
  __shared__ bf16_t Vt[64 * 64];
  __shared__ bf16_t Pl[4][16 * 64];

  // Q A-fragments (row = r), dk pattern kk*32 + g*8 (+0..7)
  const int qa = qt * 64 + w * 16 + r;
  const bf16_t* qptr = Q1 + ((size_t)b * NS + qa) * ND + h * 64;
  bf16x8 qf0 = *(const bf16x8*)(qptr + g * 8);
  bf16x8 qf1 = *(const bf16x8*)(qptr + 32 + g * 8);

  float mrun[4], lrun[4];
  f32x4 oacc[4] = {};
#pragma unroll
  for (int j = 0; j < 4; ++j) { mrun[j] = -1e30f; lrun[j] = 0.f; }

  const int qrow_base = qt * 64 + w * 16 + g * 4;  // C-layout rows

  for (int kt = 0; kt <= qt; ++kt) {
    const int k0 = kt * 64;
    // --- K staging: global_load_lds, source pre-swizzled so that the
    // swizzled read (byte = key*128 + ((dk*2)^((key&7)<<4))) sees K[key][dk].
#pragma unroll
    for (int it = 0; it < 2; ++it) {
      int idx = it * 256 + tid;
      int key = idx >> 3;
      int dkg = ((idx & 7) ^ (key & 7)) << 3;
      GLL16(K1 + ((size_t)b * NS + k0 + key) * ND + h * 64 + dkg,
            Kt + (size_t)(it * 256 + w * 64) * 8);
    }
    // --- V staging: reg-stage, write transposed + swizzled
    bf16x8 vr[2];
#pragma unroll
    for (int it = 0; it < 2; ++it) {
      int dkb = (it * 4 + w) * 8;
      vr[it] = *(const bf16x8*)(V1 + ((size_t)b * NS + k0 + l) * ND + h * 64 + dkb);
    }
#pragma unroll
    for (int it = 0; it < 2; ++it) {
      int dkb = (it * 4 + w) * 8;
#pragma unroll
      for (int jj = 0; jj < 8; ++jj) {
        int dk = dkb + jj;
        int boff = dk * 128 + ((l * 2) ^ ((dk & 7) << 4));
        *(bf16_t*)((char*)Vt + boff) = vr[it][jj];
      }
    }
    __syncthreads();

    // --- QK^T: 16x64 scores per wave
    f32x4 sacc[4] = {};
#pragma unroll
    for (int n = 0; n < 4; ++n) {
      int key = n * 16 + r;
#pragma unroll
      for (int kk = 0; kk < 2; ++kk) {
        int dk = kk * 32 + g * 8;
        int boff = key * 128 + ((dk * 2) ^ ((key & 7) << 4));
        bf16x8 kf = *(const bf16x8*)((char*)Kt + boff);
        sacc[n] = __builtin_amdgcn_mfma_f32_16x16x32_bf16(kk == 0 ? qf0 : qf1, kf, sacc[n], 0, 0, 0);
      }
    }

    // --- online softmax (rows live on 16-lane groups: row = g*4+j, col = n*16+r)
    const bool diag = (kt == qt);
    float m_new[4], esc[4], rsum[4], pv[4][4];
#pragma unroll
    for (int j = 0; j < 4; ++j) {
      float mx = -1e30f;
#pragma unroll
      for (int n = 0; n < 4; ++n) {
        float s = sacc[n][j] * 0.125f;
        if (diag && (k0 + n * 16 + r) > (qrow_base + j)) s = -1e30f;
        pv[n][j] = s;
        mx = fmaxf(mx, s);
      }
      mx = fmaxf(mx, __shfl_xor(mx, 1));
      mx = fmaxf(mx, __shfl_xor(mx, 2));
      mx = fmaxf(mx, __shfl_xor(mx, 4));
      mx = fmaxf(mx, __shfl_xor(mx, 8));
      m_new[j] = fmaxf(mrun[j], mx);
      esc[j] = __expf(mrun[j] - m_new[j]);
      mrun[j] = m_new[j];
      rsum[j] = 0.f;
    }
#pragma unroll
    for (int n = 0; n < 4; ++n)
#pragma unroll
      for (int j = 0; j < 4; ++j) {
        float p = __expf(pv[n][j] - m_new[j]);
        rsum[j] += p;
        int row = g * 4 + j, col = n * 16 + r;
        int boff = row * 128 + ((col * 2) ^ ((row & 7) << 4));
        *(bf16_t*)((char*)(Pl[w]) + boff) = (bf16_t)p;
      }
#pragma unroll
    for (int j = 0; j < 4; ++j) {
      float s = rsum[j];
      s += __shfl_xor(s, 1); s += __shfl_xor(s, 2);
      s += __shfl_xor(s, 4); s += __shfl_xor(s, 8);
      lrun[j] = lrun[j] * esc[j] + s;
    }
#pragma unroll
    for (int n = 0; n < 4; ++n)
#pragma unroll
      for (int j = 0; j < 4; ++j) oacc[n][j] *= esc[j];

    // --- PV: P (16x64) x V (64x64)
#pragma unroll
    for (int kk = 0; kk < 2; ++kk) {
      int keyb = kk * 32 + g * 8;
      int poff = r * 128 + ((keyb * 2) ^ ((r & 7) << 4));
      bf16x8 pf = *(const bf16x8*)((char*)(Pl[w]) + poff);
#pragma unroll
      for (int n = 0; n < 4; ++n) {
        int dk = n * 16 + r;
        int voff = dk * 128 + ((keyb * 2) ^ ((dk & 7) << 4));
        bf16x8 vf = *(const bf16x8*)((char*)Vt + voff);
        oacc[n] = __builtin_amdgcn_mfma_f32_16x16x32_bf16(pf, vf, oacc[n], 0, 0, 0);
      }
    }
    __syncthreads();
  }

  // epilogue: O /= l, write bf16
#pragma unroll
  for (int n = 0; n < 4; ++n) {
    int dk = n * 16 + r;
#pragma unroll
    for (int j = 0; j < 4; ++j) {
      float ov = oacc[n][j] / lrun[j];
      attn[((size_t)b * NS + qrow_base + j) * ND + h * 64 + dk] = (bf16_t)ov;
    }
  }
}

// ---------------- launch ----------------
extern "C" void kernel_launch(void* const* d_in, const int* in_sizes, int n_in,
                              void* d_out, int out_size, void* d_ws, size_t ws_size,
                              hipStream_t stream) {
  const float* q  = (const float*)d_in[0];
  const float* k  = (const float*)d_in[1];
  const float* v  = (const float*)d_in[2];
  // d_in[3] = mask (int32 tril, implemented analytically)
  const float* Wq = (const float*)d_in[4];
  const float* bq = (const float*)d_in[5];
  const float* Wk = (const float*)d_in[6];
  const float* bk = (const float*)d_in[7];
  const float* Wv = (const float*)d_in[8];
  const float* bv = (const float*)d_in[9];
  const float* Wo = (const float*)d_in[10];
  const float* bo = (const float*)d_in[11];
  float* out = (float*)d_out;

  const size_t NX = (size_t)NB * NS * ND;  // 8388608
  const size_t NW = (size_t)ND * ND;       // 1048576
  char* ws = (char*)d_ws;
  size_t off = 0;
  auto alloc = [&](size_t bytes) {
    char* p = ws + off;
    off += (bytes + 255) & ~(size_t)255;
    return p;
  };
  bf16_t* xq  = (bf16_t*)alloc(NX * 2);
  bf16_t* xk  = (bf16_t*)alloc(NX * 2);
  bf16_t* xv  = (bf16_t*)alloc(NX * 2);
  bf16_t* wqb = (bf16_t*)alloc(NW * 2);
  bf16_t* wkb = (bf16_t*)alloc(NW * 2);
  bf16_t* wvb = (bf16_t*)alloc(NW * 2);
  bf16_t* wob = (bf16_t*)alloc(NW * 2);
  bf16_t* q1  = (bf16_t*)alloc(NX * 2);
  bf16_t* k1  = (bf16_t*)alloc(NX * 2);
  bf16_t* v1  = (bf16_t*)alloc(NX * 2);
  bf16_t* at  = xq;  // xq dead after first GEMM; reuse for attn output

  dim3 blk(256);
  cvt_kernel<<<2048, blk, 0, stream>>>(q, xq, (long)NX);
  cvt_kernel<<<2048, blk, 0, stream>>>(k, xk, (long)NX);
  cvt_kernel<<<2048, blk, 0, stream>>>(v, xv, (long)NX);
  cvt_kernel<<<1024, blk, 0, stream>>>(Wq, wqb, (long)NW);
  cvt_kernel<<<1024, blk, 0, stream>>>(Wk, wkb, (long)NW);
  cvt_kernel<<<1024, blk, 0, stream>>>(Wv, wvb, (long)NW);
  cvt_kernel<<<1024, blk, 0, stream>>>(Wo, wob, (long)NW);

  dim3 gproj(ND / 128, (NB * NS) / 128);  // (8, 64)
  gemm_bt<false><<<gproj, blk, 0, stream>>>(xq, wqb, bq, q1, NB * NS, ND, ND);
  gemm_bt<false><<<gproj, blk, 0, stream>>>(xk, wkb, bk, k1, NB * NS, ND, ND);
  gemm_bt<false><<<gproj, blk, 0, stream>>>(xv, wvb, bv, v1, NB * NS, ND, ND);

  dim3 gattn(NS / 64, NH, NB);
  attn_kernel<<<gattn, blk, 0, stream>>>(q1, k1, v1, at);

  gemm_bt<true><<<gproj, blk, 0, stream>>>(at, wob, bo, out, NB * NS, ND, ND);
}

// Round 2
// 210.781 us; speedup vs baseline: 1.4666x; 1.4666x over previous
//
#include <hip/hip_runtime.h>
#include <hip/hip_bf16.h>
#include <stdint.h>

// Problem constants
constexpr int NB = 8;     // batch
constexpr int NS = 1024;  // seq
constexpr int ND = 1024;  // model dim
constexpr int NH = 16;    // heads
constexpr int NDK = 64;   // head dim
constexpr int NT = NS / 64;  // 16 q-tiles of 64 rows

typedef __bf16 bf16_t;
typedef __attribute__((ext_vector_type(8))) __bf16 bf16x8;
typedef __attribute__((ext_vector_type(4))) __bf16 bf16x4;
typedef __attribute__((ext_vector_type(4))) float f32x4;

#define GLL16(g, s) __builtin_amdgcn_global_load_lds( \
    (const __attribute__((address_space(1))) void*)(g), \
    (__attribute__((address_space(3))) void*)(s), 16, 0, 0)

// ---------------- fp32 -> bf16 converts (fused launches) ----------------
__device__ __forceinline__ void cvt_body(const float* __restrict__ s,
                                         bf16_t* __restrict__ d, long n) {
  long i0 = (long)(blockIdx.x * blockDim.x + threadIdx.x) * 4;
  long step = (long)gridDim.x * blockDim.x * 4;
  for (long i = i0; i < n; i += step) {
    float4 f = *(const float4*)(s + i);
    bf16x4 o;
    o[0] = (bf16_t)f.x; o[1] = (bf16_t)f.y; o[2] = (bf16_t)f.z; o[3] = (bf16_t)f.w;
    *(bf16x4*)(d + i) = o;
  }
}

__global__ __launch_bounds__(256) void cvt3_kernel(const float* s0, bf16_t* d0,
                                                   const float* s1, bf16_t* d1,
                                                   const float* s2, bf16_t* d2, long n) {
  const float* s = blockIdx.y == 0 ? s0 : blockIdx.y == 1 ? s1 : s2;
  bf16_t* d = blockIdx.y == 0 ? d0 : blockIdx.y == 1 ? d1 : d2;
  cvt_body(s, d, n);
}

__global__ __launch_bounds__(256) void cvt4_kernel(const float* s0, bf16_t* d0,
                                                   const float* s1, bf16_t* d1,
                                                   const float* s2, bf16_t* d2,
                                                   const float* s3, bf16_t* d3, long n) {
  const float* s = blockIdx.y == 0 ? s0 : blockIdx.y == 1 ? s1 : blockIdx.y == 2 ? s2 : s3;
  bf16_t* d = blockIdx.y == 0 ? d0 : blockIdx.y == 1 ? d1 : blockIdx.y == 2 ? d2 : d3;
  cvt_body(s, d, n);
}

// ---------------- GEMM: C[M,N] = A[M,K] @ W[N,K]^T + bias ----------------
// 128x128 tile, 4 waves (2x2 of 64x64), BK=32, mfma 16x16x32 bf16.
template<bool OUT_F32>
__device__ __forceinline__ void gemm_body(bf16_t* As, bf16_t* Bs,
                                          const bf16_t* __restrict__ A,
                                          const bf16_t* __restrict__ W,
                                          const float* __restrict__ bias,
                                          void* __restrict__ Cout,
                                          int M, int N, int K, int bx, int by) {
  const int tid = threadIdx.x;
  const int l = tid & 63, w = tid >> 6;
  const int wr = w >> 1, wc = w & 1;
  const int g = l >> 4, r = l & 15;
  const int m0 = by * 128, n0 = bx * 128;

  f32x4 acc[4][4] = {};

  for (int k0 = 0; k0 < K; k0 += 32) {
#pragma unroll
    for (int it = 0; it < 2; ++it) {
      int idx = it * 256 + tid;        // chunk 0..511 (16B each)
      int row = idx >> 2, cg = idx & 3;
      GLL16(A + (size_t)(m0 + row) * K + (k0 + cg * 8),
            As + (size_t)(it * 256 + w * 64) * 8);
      GLL16(W + (size_t)(n0 + row) * K + (k0 + cg * 8),
            Bs + (size_t)(it * 256 + w * 64) * 8);
    }
    __syncthreads();
    bf16x8 af[4], bfr[4];
#pragma unroll
    for (int m = 0; m < 4; ++m)
      af[m] = *(const bf16x8*)(As + (wr * 64 + m * 16 + r) * 32 + g * 8);
#pragma unroll
    for (int n = 0; n < 4; ++n)
      bfr[n] = *(const bf16x8*)(Bs + (wc * 64 + n * 16 + r) * 32 + g * 8);
#pragma unroll
    for (int m = 0; m < 4; ++m)
#pragma unroll
      for (int n = 0; n < 4; ++n)
        acc[m][n] = __builtin_amdgcn_mfma_f32_16x16x32_bf16(af[m], bfr[n], acc[m][n], 0, 0, 0);
    __syncthreads();
  }

#pragma unroll
  for (int n = 0; n < 4; ++n) {
    int col = n0 + wc * 64 + n * 16 + r;
    float bv = bias[col];
#pragma unroll
    for (int m = 0; m < 4; ++m) {
      int row0 = m0 + wr * 64 + m * 16 + g * 4;
#pragma unroll
      for (int j = 0; j < 4; ++j) {
        float vv = acc[m][n][j] + bv;
        if (OUT_F32)
          ((float*)Cout)[(size_t)(row0 + j) * N + col] = vv;
        else
          ((bf16_t*)Cout)[(size_t)(row0 + j) * N + col] = (bf16_t)vv;
      }
    }
  }
}

template<bool OUT_F32>
__global__ __launch_bounds__(256) void gemm_bt(const bf16_t* __restrict__ A,
                                               const bf16_t* __restrict__ W,
                                               const float* __restrict__ bias,
                                               void* __restrict__ Cout,
                                               int M, int N, int K) {
  __shared__ bf16_t As[128 * 32];
  __shared__ bf16_t Bs[128 * 32];
  gemm_body<OUT_F32>(As, Bs, A, W, bias, Cout, M, N, K, blockIdx.x, blockIdx.y);
}

__global__ __launch_bounds__(256) void gemm_qkv(
    const bf16_t* A0, const bf16_t* W0, const float* b0, bf16_t* C0,
    const bf16_t* A1, const bf16_t* W1, const float* b1, bf16_t* C1,
    const bf16_t* A2, const bf16_t* W2, const float* b2, bf16_t* C2,
    int M, int N, int K) {
  __shared__ bf16_t As[128 * 32];
  __shared__ bf16_t Bs[128 * 32];
  const int z = blockIdx.z;
  const bf16_t* A = z == 0 ? A0 : z == 1 ? A1 : A2;
  const bf16_t* W = z == 0 ? W0 : z == 1 ? W1 : W2;
  const float* bb = z == 0 ? b0 : z == 1 ? b1 : b2;
  bf16_t* C = z == 0 ? C0 : z == 1 ? C1 : C2;
  gemm_body<false>(As, Bs, A, W, bb, (void*)C, M, N, K, blockIdx.x, blockIdx.y);
}

// ---------------- causal flash attention (2-phase pipelined) ----------------
// 1024 blocks: (pair in [0,8), h, b) with XCD-grouped bijective swizzle.
// Each block does q-tiles {pair, 15-pair} sequentially (uniform 17 kt-iters).
// Per q-tile: double-buffered K (global_load_lds, pre-swizzled source) and
// V (reg-staged, transposed + XOR-swizzled LDS); prefetch of tile kt+1 issued
// after the barrier, before compute of tile kt — global latency hides under
// QK/softmax/PV. One barrier per iteration.
__global__ __launch_bounds__(256, 4) void attn_kernel(const bf16_t* __restrict__ Q1,
                                                      const bf16_t* __restrict__ K1,
                                                      const bf16_t* __restrict__ V1,
                                                      bf16_t* __restrict__ attn) {
  __shared__ bf16_t Kt[2][64 * 64];
  __shared__ bf16_t Vt[2][64 * 64];
  __shared__ bf16_t Pl[4][16 * 64];

  const int tid = threadIdx.x;
  const int l = tid & 63, w = tid >> 6;
  const int g = l >> 4, r = l & 15;

  // bijective XCD swizzle (nwg=1024, divisible by 8): all blocks of a given
  // (b,h) land on one XCD so K/V stay L2-resident there.
  const int o = blockIdx.x;
  const int os = (o & 7) * 128 + (o >> 3);
  const int pair = os & 7, hb = os >> 3;
  const int h = hb & 15, b = hb >> 4;

  for (int ph = 0; ph < 2; ++ph) {
    const int qt = ph ? (NT - 1 - pair) : pair;

    const int qa = qt * 64 + w * 16 + r;
    const bf16_t* qptr = Q1 + ((size_t)b * NS + qa) * ND + h * 64;
    bf16x8 qf0 = *(const bf16x8*)(qptr + g * 8);
    bf16x8 qf1 = *(const bf16x8*)(qptr + 32 + g * 8);

    float mrun[4], lrun[4];
    f32x4 oacc[4] = {};
#pragma unroll
    for (int j = 0; j < 4; ++j) { mrun[j] = -1e30f; lrun[j] = 0.f; }
    const int qrow_base = qt * 64 + w * 16 + g * 4;

    __syncthreads();  // prior phase's readers done before we restage buffers

    // prologue: stage tile 0 into buffer 0
    bf16x8 vr0, vr1;
    {
#pragma unroll
      for (int it = 0; it < 2; ++it) {
        int idx = it * 256 + tid;
        int key = idx >> 3;
        int dkg = ((idx & 7) ^ (key & 7)) << 3;
        GLL16(K1 + ((size_t)b * NS + key) * ND + h * 64 + dkg,
              &Kt[0][(it * 256 + w * 64) * 8]);
      }
      vr0 = *(const bf16x8*)(V1 + ((size_t)b * NS + l) * ND + h * 64 + w * 8);
      vr1 = *(const bf16x8*)(V1 + ((size_t)b * NS + l) * ND + h * 64 + (4 + w) * 8);
    }

    for (int kt = 0; kt <= qt; ++kt) {
      const int p = kt & 1;
      const int k0 = kt * 64;

      // commit V regs -> Vt[p] (transposed + swizzled); compiler inserts the
      // counted vmcnt for vr0/vr1 (which also covers the older K GLLs).
#pragma unroll
      for (int it = 0; it < 2; ++it) {
        int dkb = (it * 4 + w) * 8;
#pragma unroll
        for (int jj = 0; jj < 8; ++jj) {
          int dk = dkb + jj;
          int boff = dk * 128 + ((l * 2) ^ ((dk & 7) << 4));
          *(bf16_t*)((char*)Vt[p] + boff) = (it ? vr1 : vr0)[jj];
        }
      }
      __syncthreads();  // tile kt fully staged & visible

      // prefetch tile kt+1 into buffers p^1 (lands during compute below)
      if (kt < qt) {
        const int k0n = k0 + 64;
#pragma unroll
        for (int it = 0; it < 2; ++it) {
          int idx = it * 256 + tid;
          int key = idx >> 3;
          int dkg = ((idx & 7) ^ (key & 7)) << 3;
          GLL16(K1 + ((size_t)b * NS + k0n + key) * ND + h * 64 + dkg,
                &Kt[p ^ 1][(it * 256 + w * 64) * 8]);
        }
        vr0 = *(const bf16x8*)(V1 + ((size_t)b * NS + k0n + l) * ND + h * 64 + w * 8);
        vr1 = *(const bf16x8*)(V1 + ((size_t)b * NS + k0n + l) * ND + h * 64 + (4 + w) * 8);
      }

      // --- QK^T: 16x64 scores per wave
      f32x4 sacc[4] = {};
#pragma unroll
      for (int n = 0; n < 4; ++n) {
        int key = n * 16 + r;
#pragma unroll
        for (int kk = 0; kk < 2; ++kk) {
          int dk2 = kk * 32 + g * 8;
          int boff = key * 128 + ((dk2 * 2) ^ ((key & 7) << 4));
          bf16x8 kf = *(const bf16x8*)((char*)Kt[p] + boff);
          sacc[n] = __builtin_amdgcn_mfma_f32_16x16x32_bf16(kk == 0 ? qf0 : qf1, kf, sacc[n], 0, 0, 0);
        }
      }

      // --- online softmax (C-layout: row = g*4+j, col = n*16+r)
      const bool diag = (kt == qt);
      float m_new[4], esc[4];
#pragma unroll
      for (int j = 0; j < 4; ++j) {
        float mx = -1e30f;
#pragma unroll
        for (int n = 0; n < 4; ++n) {
          float s = sacc[n][j] * 0.125f;
          if (diag && (k0 + n * 16 + r) > (qrow_base + j)) s = -1e30f;
          sacc[n][j] = s;
          mx = fmaxf(mx, s);
        }
        mx = fmaxf(mx, __shfl_xor(mx, 1));
        mx = fmaxf(mx, __shfl_xor(mx, 2));
        mx = fmaxf(mx, __shfl_xor(mx, 4));
        mx = fmaxf(mx, __shfl_xor(mx, 8));
        m_new[j] = fmaxf(mrun[j], mx);
        esc[j] = __expf(mrun[j] - m_new[j]);
        mrun[j] = m_new[j];
      }
      float rsum[4] = {0.f, 0.f, 0.f, 0.f};
#pragma unroll
      for (int n = 0; n < 4; ++n)
#pragma unroll
        for (int j = 0; j < 4; ++j) {
          float pe = __expf(sacc[n][j] - m_new[j]);
          rsum[j] += pe;
          int row = g * 4 + j, col = n * 16 + r;
          int boff = row * 128 + ((col * 2) ^ ((row & 7) << 4));
          *(bf16_t*)((char*)Pl[w] + boff) = (bf16_t)pe;
        }
#pragma unroll
      for (int j = 0; j < 4; ++j) {
        float s2 = rsum[j];
        s2 += __shfl_xor(s2, 1); s2 += __shfl_xor(s2, 2);
        s2 += __shfl_xor(s2, 4); s2 += __shfl_xor(s2, 8);
        lrun[j] = lrun[j] * esc[j] + s2;
      }
#pragma unroll
      for (int n = 0; n < 4; ++n)
#pragma unroll
        for (int j = 0; j < 4; ++j) oacc[n][j] *= esc[j];

      // --- PV: P (16x64) x V (64x64)
#pragma unroll
      for (int kk = 0; kk < 2; ++kk) {
        int keyb = kk * 32 + g * 8;
        int poff = r * 128 + ((keyb * 2) ^ ((r & 7) << 4));
        bf16x8 pf = *(const bf16x8*)((char*)Pl[w] + poff);
#pragma unroll
        for (int n = 0; n < 4; ++n) {
          int dk2 = n * 16 + r;
          int voff = dk2 * 128 + ((keyb * 2) ^ ((dk2 & 7) << 4));
          bf16x8 vf = *(const bf16x8*)((char*)Vt[p] + voff);
          oacc[n] = __builtin_amdgcn_mfma_f32_16x16x32_bf16(pf, vf, oacc[n], 0, 0, 0);
        }
      }
    }  // kt

    // epilogue: O /= l, write bf16
#pragma unroll
    for (int n = 0; n < 4; ++n) {
      int dk2 = n * 16 + r;
#pragma unroll
      for (int j = 0; j < 4; ++j) {
        float ov = oacc[n][j] / lrun[j];
        attn[((size_t)b * NS + qrow_base + j) * ND + h * 64 + dk2] = (bf16_t)ov;
      }
    }
  }  // ph
}

// ---------------- launch ----------------
extern "C" void kernel_launch(void* const* d_in, const int* in_sizes, int n_in,
                              void* d_out, int out_size, void* d_ws, size_t ws_size,
                              hipStream_t stream) {
  const float* q  = (const float*)d_in[0];
  const float* k  = (const float*)d_in[1];
  const float* v  = (const float*)d_in[2];
  // d_in[3] = mask (int32 tril, implemented analytically)
  const float* Wq = (const float*)d_in[4];
  const float* bq = (const float*)d_in[5];
  const float* Wk = (const float*)d_in[6];
  const float* bk = (const float*)d_in[7];
  const float* Wv = (const float*)d_in[8];
  const float* bv = (const float*)d_in[9];
  const float* Wo = (const float*)d_in[10];
  const float* bo = (const float*)d_in[11];
  float* out = (float*)d_out;

  const size_t NX = (size_t)NB * NS * ND;  // 8388608
  const size_t NW = (size_t)ND * ND;       // 1048576
  char* ws = (char*)d_ws;
  size_t off = 0;
  auto alloc = [&](size_t bytes) {
    char* p = ws + off;
    off += (bytes + 255) & ~(size_t)255;
    return p;
  };
  bf16_t* xq  = (bf16_t*)alloc(NX * 2);
  bf16_t* xk  = (bf16_t*)alloc(NX * 2);
  bf16_t* xv  = (bf16_t*)alloc(NX * 2);
  bf16_t* wqb = (bf16_t*)alloc(NW * 2);
  bf16_t* wkb = (bf16_t*)alloc(NW * 2);
  bf16_t* wvb = (bf16_t*)alloc(NW * 2);
  bf16_t* wob = (bf16_t*)alloc(NW * 2);
  bf16_t* q1  = (bf16_t*)alloc(NX * 2);
  bf16_t* k1  = (bf16_t*)alloc(NX * 2);
  bf16_t* v1  = (bf16_t*)alloc(NX * 2);
  bf16_t* at  = xq;  // xq dead after QKV GEMMs; reuse for attn output

  dim3 blk(256);
  cvt3_kernel<<<dim3(1024, 3), blk, 0, stream>>>(q, xq, k, xk, v, xv, (long)NX);
  cvt4_kernel<<<dim3(128, 4), blk, 0, stream>>>(Wq, wqb, Wk, wkb, Wv, wvb, Wo, wob, (long)NW);

  gemm_qkv<<<dim3(ND / 128, (NB * NS) / 128, 3), blk, 0, stream>>>(
      xq, wqb, bq, q1, xk, wkb, bk, k1, xv, wvb, bv, v1, NB * NS, ND, ND);

  attn_kernel<<<dim3((NT / 2) * NH * NB), blk, 0, stream>>>(q1, k1, v1, at);

  gemm_bt<true><<<dim3(ND / 128, (NB * NS) / 128), blk, 0, stream>>>(
      at, wob, bo, out, NB * NS, ND, ND);
}

// Round 3
// 207.954 us; speedup vs baseline: 1.4866x; 1.0136x over previous
//
#include <hip/hip_runtime.h>
#include <hip/hip_bf16.h>
#include <stdint.h>

// Problem constants
constexpr int NB = 8;     // batch
constexpr int NS = 1024;  // seq
constexpr int ND = 1024;  // model dim
constexpr int NH = 16;    // heads
constexpr int NDK = 64;   // head dim
constexpr int NT = NS / 64;  // 16 q-tiles of 64 rows

typedef __bf16 bf16_t;
typedef __attribute__((ext_vector_type(8))) __bf16 bf16x8;
typedef __attribute__((ext_vector_type(4))) __bf16 bf16x4;
typedef __attribute__((ext_vector_type(4))) float f32x4;

#define GLL16(g, s) __builtin_amdgcn_global_load_lds( \
    (const __attribute__((address_space(1))) void*)(g), \
    (__attribute__((address_space(3))) void*)(s), 16, 0, 0)

// ---------------- fp32 -> bf16 converts (fused launches) ----------------
__device__ __forceinline__ void cvt_body(const float* __restrict__ s,
                                         bf16_t* __restrict__ d, long n) {
  long i0 = (long)(blockIdx.x * blockDim.x + threadIdx.x) * 4;
  long step = (long)gridDim.x * blockDim.x * 4;
  for (long i = i0; i < n; i += step) {
    float4 f = *(const float4*)(s + i);
    bf16x4 o;
    o[0] = (bf16_t)f.x; o[1] = (bf16_t)f.y; o[2] = (bf16_t)f.z; o[3] = (bf16_t)f.w;
    *(bf16x4*)(d + i) = o;
  }
}

__global__ __launch_bounds__(256) void cvt3_kernel(const float* s0, bf16_t* d0,
                                                   const float* s1, bf16_t* d1,
                                                   const float* s2, bf16_t* d2, long n) {
  const float* s = blockIdx.y == 0 ? s0 : blockIdx.y == 1 ? s1 : s2;
  bf16_t* d = blockIdx.y == 0 ? d0 : blockIdx.y == 1 ? d1 : d2;
  cvt_body(s, d, n);
}

__global__ __launch_bounds__(256) void cvt4_kernel(const float* s0, bf16_t* d0,
                                                   const float* s1, bf16_t* d1,
                                                   const float* s2, bf16_t* d2,
                                                   const float* s3, bf16_t* d3, long n) {
  const float* s = blockIdx.y == 0 ? s0 : blockIdx.y == 1 ? s1 : blockIdx.y == 2 ? s2 : s3;
  bf16_t* d = blockIdx.y == 0 ? d0 : blockIdx.y == 1 ? d1 : blockIdx.y == 2 ? d2 : d3;
  cvt_body(s, d, n);
}

// ---------------- GEMM: C[M,N] = A[M,K] @ W[N,K]^T + bias ----------------
// 128x128 tile, 4 waves (2x2 of 64x64 each), BK=64, mfma 16x16x32 bf16.
// 2-phase double-buffered staging (T3-minimum): barrier drains the stage
// issued one compute-phase earlier; prefetch of K-tile t+1 issued right after
// the barrier, before computing tile t. LDS rows are 128 B with st-16x32-style
// XOR swizzle: slot = chunk ^ (row&7); global_load_lds writes linearly, so the
// global SOURCE is pre-swizzled (rule: both-sides-or-neither).
template<bool OUT_F32>
__device__ __forceinline__ void gemm_body(bf16_t* S,  // [4][128*64]: A0,B0,A1,B1
                                          const bf16_t* __restrict__ A,
                                          const bf16_t* __restrict__ W,
                                          const float* __restrict__ bias,
                                          void* __restrict__ Cout,
                                          int M, int N, int K, int bx, int by) {
  const int tid = threadIdx.x;
  const int l = tid & 63, w = tid >> 6;
  const int wr = w >> 1, wc = w & 1;
  const int g = l >> 4, r = l & 15;
  const int m0 = by * 128, n0 = bx * 128;

  bf16_t* As[2] = {S, S + 2 * 8192};
  bf16_t* Bs[2] = {S + 8192, S + 3 * 8192};

  auto stage = [&](const bf16_t* __restrict__ X, int x0, int k0, bf16_t* dst) {
#pragma unroll
    for (int it = 0; it < 4; ++it) {
      int idx = it * 256 + tid;           // chunk 0..1023 (16B each)
      int row = idx >> 3;                 // 128 rows x 8 chunks
      int c = (idx & 7) ^ (row & 7);      // pre-swizzled source chunk
      GLL16(X + (size_t)(x0 + row) * K + k0 + c * 8,
            dst + (size_t)(it * 256 + w * 64) * 8);
    }
  };

  f32x4 acc[4][4] = {};
  const int NKT = K >> 6;

  stage(A, m0, 0, As[0]);
  stage(W, n0, 0, Bs[0]);

  for (int t = 0; t < NKT; ++t) {
    const int p = t & 1;
    __syncthreads();  // hipcc emits vmcnt(0) drain: buffer p fully staged
    if (t + 1 < NKT) {
      stage(A, m0, (t + 1) << 6, As[p ^ 1]);
      stage(W, n0, (t + 1) << 6, Bs[p ^ 1]);
    }
#pragma unroll
    for (int kk = 0; kk < 2; ++kk) {
      bf16x8 af[4], bw[4];
#pragma unroll
      for (int m = 0; m < 4; ++m) {
        int row = wr * 64 + m * 16 + r;
        af[m] = *(const bf16x8*)(As[p] + row * 64 + (((kk * 4 + g) ^ (row & 7)) << 3));
      }
#pragma unroll
      for (int n = 0; n < 4; ++n) {
        int row = wc * 64 + n * 16 + r;
        bw[n] = *(const bf16x8*)(Bs[p] + row * 64 + (((kk * 4 + g) ^ (row & 7)) << 3));
      }
#pragma unroll
      for (int m = 0; m < 4; ++m)
#pragma unroll
        for (int n = 0; n < 4; ++n)
          acc[m][n] = __builtin_amdgcn_mfma_f32_16x16x32_bf16(af[m], bw[n], acc[m][n], 0, 0, 0);
    }
  }

#pragma unroll
  for (int n = 0; n < 4; ++n) {
    int col = n0 + wc * 64 + n * 16 + r;
    float bv = bias[col];
#pragma unroll
    for (int m = 0; m < 4; ++m) {
      int row0 = m0 + wr * 64 + m * 16 + g * 4;
#pragma unroll
      for (int j = 0; j < 4; ++j) {
        float vv = acc[m][n][j] + bv;
        if (OUT_F32)
          ((float*)Cout)[(size_t)(row0 + j) * N + col] = vv;
        else
          ((bf16_t*)Cout)[(size_t)(row0 + j) * N + col] = (bf16_t)vv;
      }
    }
  }
}

// O-projection: grid 512 (1-D), XCD-grouped bijective swizzle (512 % 8 == 0).
__global__ __launch_bounds__(256) void gemm_bt(const bf16_t* __restrict__ A,
                                               const bf16_t* __restrict__ W,
                                               const float* __restrict__ bias,
                                               float* __restrict__ Cout,
                                               int M, int N, int K) {
  __shared__ bf16_t S[4][128 * 64];
  const int o = blockIdx.x;
  const int xcd = o & 7, s = o >> 3;   // s in [0,64)
  const int bx = s & 7, u = s >> 3;    // u in [0,8)
  const int by = xcd + 8 * u;          // all bx of one by share an XCD
  gemm_body<true>(&S[0][0], A, W, bias, (void*)Cout, M, N, K, bx, by);
}

// QKV: grid 1536 (1-D). Per XCD: 8 by-panels x 8 bx x 3 z — A-panel fetched
// once per XCD, W (2 MB) stays L2-resident.
__global__ __launch_bounds__(256) void gemm_qkv(
    const bf16_t* A0, const bf16_t* W0, const float* b0, bf16_t* C0,
    const bf16_t* A1, const bf16_t* W1, const float* b1, bf16_t* C1,
    const bf16_t* A2, const bf16_t* W2, const float* b2, bf16_t* C2,
    int M, int N, int K) {
  __shared__ bf16_t S[4][128 * 64];
  const int o = blockIdx.x;
  const int xcd = o & 7, s = o >> 3;   // s in [0,192)
  const int bx = s & 7, t2 = s >> 3;   // t2 in [0,24)
  const int by = xcd + 8 * (t2 & 7);
  const int z = t2 >> 3;               // 0..2
  const bf16_t* A = z == 0 ? A0 : z == 1 ? A1 : A2;
  const bf16_t* W = z == 0 ? W0 : z == 1 ? W1 : W2;
  const float* bb = z == 0 ? b0 : z == 1 ? b1 : b2;
  bf16_t* C = z == 0 ? C0 : z == 1 ? C1 : C2;
  gemm_body<false>(&S[0][0], A, W, bb, (void*)C, M, N, K, bx, by);
}

// ---------------- causal flash attention (2-phase pipelined) ----------------
__global__ __launch_bounds__(256, 4) void attn_kernel(const bf16_t* __restrict__ Q1,
                                                      const bf16_t* __restrict__ K1,
                                                      const bf16_t* __restrict__ V1,
                                                      bf16_t* __restrict__ attn) {
  __shared__ bf16_t Kt[2][64 * 64];
  __shared__ bf16_t Vt[2][64 * 64];
  __shared__ bf16_t Pl[4][16 * 64];

  const int tid = threadIdx.x;
  const int l = tid & 63, w = tid >> 6;
  const int g = l >> 4, r = l & 15;

  // bijective XCD swizzle (nwg=1024): all blocks of a given (b,h) on one XCD.
  const int o = blockIdx.x;
  const int os = (o & 7) * 128 + (o >> 3);
  const int pair = os & 7, hb = os >> 3;
  const int h = hb & 15, b = hb >> 4;

  for (int ph = 0; ph < 2; ++ph) {
    const int qt = ph ? (NT - 1 - pair) : pair;

    const int qa = qt * 64 + w * 16 + r;
    const bf16_t* qptr = Q1 + ((size_t)b * NS + qa) * ND + h * 64;
    bf16x8 qf0 = *(const bf16x8*)(qptr + g * 8);
    bf16x8 qf1 = *(const bf16x8*)(qptr + 32 + g * 8);

    float mrun[4], lrun[4];
    f32x4 oacc[4] = {};
#pragma unroll
    for (int j = 0; j < 4; ++j) { mrun[j] = -1e30f; lrun[j] = 0.f; }
    const int qrow_base = qt * 64 + w * 16 + g * 4;

    __syncthreads();  // prior phase's readers done before we restage buffers

    // prologue: stage tile 0 into buffer 0
    bf16x8 vr0, vr1;
    {
#pragma unroll
      for (int it = 0; it < 2; ++it) {
        int idx = it * 256 + tid;
        int key = idx >> 3;
        int dkg = ((idx & 7) ^ (key & 7)) << 3;
        GLL16(K1 + ((size_t)b * NS + key) * ND + h * 64 + dkg,
              &Kt[0][(it * 256 + w * 64) * 8]);
      }
      vr0 = *(const bf16x8*)(V1 + ((size_t)b * NS + l) * ND + h * 64 + w * 8);
      vr1 = *(const bf16x8*)(V1 + ((size_t)b * NS + l) * ND + h * 64 + (4 + w) * 8);
    }

    for (int kt = 0; kt <= qt; ++kt) {
      const int p = kt & 1;
      const int k0 = kt * 64;

      // commit V regs -> Vt[p] (transposed + swizzled)
#pragma unroll
      for (int it = 0; it < 2; ++it) {
        int dkb = (it * 4 + w) * 8;
#pragma unroll
        for (int jj = 0; jj < 8; ++jj) {
          int dk = dkb + jj;
          int boff = dk * 128 + ((l * 2) ^ ((dk & 7) << 4));
          *(bf16_t*)((char*)Vt[p] + boff) = (it ? vr1 : vr0)[jj];
        }
      }
      __syncthreads();  // tile kt fully staged & visible

      // prefetch tile kt+1 into buffers p^1 (lands during compute below)
      if (kt < qt) {
        const int k0n = k0 + 64;
#pragma unroll
        for (int it = 0; it < 2; ++it) {
          int idx = it * 256 + tid;
          int key = idx >> 3;
          int dkg = ((idx & 7) ^ (key & 7)) << 3;
          GLL16(K1 + ((size_t)b * NS + k0n + key) * ND + h * 64 + dkg,
                &Kt[p ^ 1][(it * 256 + w * 64) * 8]);
        }
        vr0 = *(const bf16x8*)(V1 + ((size_t)b * NS + k0n + l) * ND + h * 64 + w * 8);
        vr1 = *(const bf16x8*)(V1 + ((size_t)b * NS + k0n + l) * ND + h * 64 + (4 + w) * 8);
      }

      // --- QK^T: 16x64 scores per wave
      f32x4 sacc[4] = {};
      __builtin_amdgcn_s_setprio(1);
#pragma unroll
      for (int n = 0; n < 4; ++n) {
        int key = n * 16 + r;
#pragma unroll
        for (int kk = 0; kk < 2; ++kk) {
          int dk2 = kk * 32 + g * 8;
          int boff = key * 128 + ((dk2 * 2) ^ ((key & 7) << 4));
          bf16x8 kf = *(const bf16x8*)((char*)Kt[p] + boff);
          sacc[n] = __builtin_amdgcn_mfma_f32_16x16x32_bf16(kk == 0 ? qf0 : qf1, kf, sacc[n], 0, 0, 0);
        }
      }
      __builtin_amdgcn_s_setprio(0);

      // --- online softmax (C-layout: row = g*4+j, col = n*16+r)
      const bool diag = (kt == qt);
      float m_new[4], esc[4];
#pragma unroll
      for (int j = 0; j < 4; ++j) {
        float mx = -1e30f;
#pragma unroll
        for (int n = 0; n < 4; ++n) {
          float s = sacc[n][j] * 0.125f;
          if (diag && (k0 + n * 16 + r) > (qrow_base + j)) s = -1e30f;
          sacc[n][j] = s;
          mx = fmaxf(mx, s);
        }
        mx = fmaxf(mx, __shfl_xor(mx, 1));
        mx = fmaxf(mx, __shfl_xor(mx, 2));
        mx = fmaxf(mx, __shfl_xor(mx, 4));
        mx = fmaxf(mx, __shfl_xor(mx, 8));
        m_new[j] = fmaxf(mrun[j], mx);
        esc[j] = __expf(mrun[j] - m_new[j]);
        mrun[j] = m_new[j];
      }
      float rsum[4] = {0.f, 0.f, 0.f, 0.f};
#pragma unroll
      for (int n = 0; n < 4; ++n)
#pragma unroll
        for (int j = 0; j < 4; ++j) {
          float pe = __expf(sacc[n][j] - m_new[j]);
          rsum[j] += pe;
          int row = g * 4 + j, col = n * 16 + r;
          int boff = row * 128 + ((col * 2) ^ ((row & 7) << 4));
          *(bf16_t*)((char*)Pl[w] + boff) = (bf16_t)pe;
        }
#pragma unroll
      for (int j = 0; j < 4; ++j) {
        float s2 = rsum[j];
        s2 += __shfl_xor(s2, 1); s2 += __shfl_xor(s2, 2);
        s2 += __shfl_xor(s2, 4); s2 += __shfl_xor(s2, 8);
        lrun[j] = lrun[j] * esc[j] + s2;
      }
#pragma unroll
      for (int n = 0; n < 4; ++n)
#pragma unroll
        for (int j = 0; j < 4; ++j) oacc[n][j] *= esc[j];

      // --- PV: P (16x64) x V (64x64)
      __builtin_amdgcn_s_setprio(1);
#pragma unroll
      for (int kk = 0; kk < 2; ++kk) {
        int keyb = kk * 32 + g * 8;
        int poff = r * 128 + ((keyb * 2) ^ ((r & 7) << 4));
        bf16x8 pf = *(const bf16x8*)((char*)Pl[w] + poff);
#pragma unroll
        for (int n = 0; n < 4; ++n) {
          int dk2 = n * 16 + r;
          int voff = dk2 * 128 + ((keyb * 2) ^ ((dk2 & 7) << 4));
          bf16x8 vf = *(const bf16x8*)((char*)Vt[p] + voff);
          oacc[n] = __builtin_amdgcn_mfma_f32_16x16x32_bf16(pf, vf, oacc[n], 0, 0, 0);
        }
      }
      __builtin_amdgcn_s_setprio(0);
    }  // kt

    // epilogue: O /= l, write bf16
#pragma unroll
    for (int n = 0; n < 4; ++n) {
      int dk2 = n * 16 + r;
#pragma unroll
      for (int j = 0; j < 4; ++j) {
        float ov = oacc[n][j] / lrun[j];
        attn[((size_t)b * NS + qrow_base + j) * ND + h * 64 + dk2] = (bf16_t)ov;
      }
    }
  }  // ph
}

// ---------------- launch ----------------
extern "C" void kernel_launch(void* const* d_in, const int* in_sizes, int n_in,
                              void* d_out, int out_size, void* d_ws, size_t ws_size,
                              hipStream_t stream) {
  const float* q  = (const float*)d_in[0];
  const float* k  = (const float*)d_in[1];
  const float* v  = (const float*)d_in[2];
  // d_in[3] = mask (int32 tril, implemented analytically)
  const float* Wq = (const float*)d_in[4];
  const float* bq = (const float*)d_in[5];
  const float* Wk = (const float*)d_in[6];
  const float* bk = (const float*)d_in[7];
  const float* Wv = (const float*)d_in[8];
  const float* bv = (const float*)d_in[9];
  const float* Wo = (const float*)d_in[10];
  const float* bo = (const float*)d_in[11];
  float* out = (float*)d_out;

  const size_t NX = (size_t)NB * NS * ND;  // 8388608
  const size_t NW = (size_t)ND * ND;       // 1048576
  char* ws = (char*)d_ws;
  size_t off = 0;
  auto alloc = [&](size_t bytes) {
    char* p = ws + off;
    off += (bytes + 255) & ~(size_t)255;
    return p;
  };
  bf16_t* xq  = (bf16_t*)alloc(NX * 2);
  bf16_t* xk  = (bf16_t*)alloc(NX * 2);
  bf16_t* xv  = (bf16_t*)alloc(NX * 2);
  bf16_t* wqb = (bf16_t*)alloc(NW * 2);
  bf16_t* wkb = (bf16_t*)alloc(NW * 2);
  bf16_t* wvb = (bf16_t*)alloc(NW * 2);
  bf16_t* wob = (bf16_t*)alloc(NW * 2);
  bf16_t* q1  = (bf16_t*)alloc(NX * 2);
  bf16_t* k1  = (bf16_t*)alloc(NX * 2);
  bf16_t* v1  = (bf16_t*)alloc(NX * 2);
  bf16_t* at  = xq;  // xq dead after QKV GEMMs; reuse for attn output

  dim3 blk(256);
  cvt3_kernel<<<dim3(1024, 3), blk, 0, stream>>>(q, xq, k, xk, v, xv, (long)NX);
  cvt4_kernel<<<dim3(128, 4), blk, 0, stream>>>(Wq, wqb, Wk, wkb, Wv, wvb, Wo, wob, (long)NW);

  gemm_qkv<<<dim3(1536), blk, 0, stream>>>(
      xq, wqb, bq, q1, xk, wkb, bk, k1, xv, wvb, bv, v1, NB * NS, ND, ND);

  attn_kernel<<<dim3((NT / 2) * NH * NB), blk, 0, stream>>>(q1, k1, v1, at);

  gemm_bt<<<dim3(512), blk, 0, stream>>>(at, wob, bo, out, NB * NS, ND, ND);
}

// Round 4
// 181.672 us; speedup vs baseline: 1.7016x; 1.1447x over previous
//
#include <hip/hip_runtime.h>
#include <hip/hip_bf16.h>
#include <stdint.h>

// Problem constants
constexpr int NB = 8;     // batch
constexpr int NS = 1024;  // seq
constexpr int ND = 1024;  // model dim
constexpr int NH = 16;    // heads
constexpr int NDK = 64;   // head dim
constexpr int NT = NS / 64;  // 16 q-tiles of 64 rows

typedef __bf16 bf16_t;
typedef __attribute__((ext_vector_type(8))) __bf16 bf16x8;
typedef __attribute__((ext_vector_type(4))) __bf16 bf16x4;
typedef __attribute__((ext_vector_type(4))) float f32x4;

#define GLL16(g, s) __builtin_amdgcn_global_load_lds( \
    (const __attribute__((address_space(1))) void*)(g), \
    (__attribute__((address_space(3))) void*)(s), 16, 0, 0)

// ---------------- fp32 -> bf16 converts (fused launches) ----------------
__device__ __forceinline__ void cvt_body(const float* __restrict__ s,
                                         bf16_t* __restrict__ d, long n) {
  long i0 = (long)(blockIdx.x * blockDim.x + threadIdx.x) * 4;
  long step = (long)gridDim.x * blockDim.x * 4;
  for (long i = i0; i < n; i += step) {
    float4 f = *(const float4*)(s + i);
    bf16x4 o;
    o[0] = (bf16_t)f.x; o[1] = (bf16_t)f.y; o[2] = (bf16_t)f.z; o[3] = (bf16_t)f.w;
    *(bf16x4*)(d + i) = o;
  }
}

__global__ __launch_bounds__(256) void cvt3_kernel(const float* s0, bf16_t* d0,
                                                   const float* s1, bf16_t* d1,
                                                   const float* s2, bf16_t* d2, long n) {
  const float* s = blockIdx.y == 0 ? s0 : blockIdx.y == 1 ? s1 : s2;
  bf16_t* d = blockIdx.y == 0 ? d0 : blockIdx.y == 1 ? d1 : d2;
  cvt_body(s, d, n);
}

__global__ __launch_bounds__(256) void cvt4_kernel(const float* s0, bf16_t* d0,
                                                   const float* s1, bf16_t* d1,
                                                   const float* s2, bf16_t* d2,
                                                   const float* s3, bf16_t* d3, long n) {
  const float* s = blockIdx.y == 0 ? s0 : blockIdx.y == 1 ? s1 : blockIdx.y == 2 ? s2 : s3;
  bf16_t* d = blockIdx.y == 0 ? d0 : blockIdx.y == 1 ? d1 : blockIdx.y == 2 ? d2 : d3;
  cvt_body(s, d, n);
}

// ---------------- GEMM: C[M,N] = A[M,K] @ W[N,K]^T + bias ----------------
// 256x128 tile, 8 waves (2M x 4N, per-wave 128x32), BK=64, mfma 16x16x32.
// Triple-buffered LDS (144 KB, 1 block/CU), prefetch distance 2, counted
// vmcnt (T4): at iter t, in-flight = t,t+1,t+2 (6 loads/thread each);
// vmcnt(12) retires exactly tile t's loads. Raw s_barrier (no implicit
// vmcnt(0) drain). XOR-swizzled LDS rows (128 B) with pre-swizzled
// global_load_lds source (both-sides rule) — 0 bank conflicts (verified R3).
// Buffer q layout: A tile (256x64) at S+q*24576, B tile (128x64) at +16384.
template<bool OUT_F32>
__device__ __forceinline__ void gemm_body(bf16_t* S,
                                          const bf16_t* __restrict__ A,
                                          const bf16_t* __restrict__ W,
                                          const float* __restrict__ bias,
                                          void* __restrict__ Cout,
                                          int M, int N, int K, int bx, int by) {
  const int tid = threadIdx.x;           // 0..511
  const int l = tid & 63, w = tid >> 6;  // 8 waves
  const int wr = w >> 2, wc = w & 3;
  const int g = l >> 4, r = l & 15;
  const int m0 = by * 256, n0 = bx * 128;
  const int wbase = (tid & 448) * 8;     // w*64*8 elements (wave-uniform LDS base)

  auto stage = [&](int q, int t) {
    const int k0 = t << 6;
    bf16_t* As = S + q * 24576;
    bf16_t* Bs = As + 16384;
#pragma unroll
    for (int it = 0; it < 4; ++it) {       // A: 256 rows x 8 chunks
      int idx = it * 512 + tid;
      int row = idx >> 3, c = (idx & 7) ^ (row & 7);
      GLL16(A + (size_t)(m0 + row) * K + k0 + c * 8, As + it * 4096 + wbase);
    }
#pragma unroll
    for (int it = 0; it < 2; ++it) {       // B: 128 rows x 8 chunks
      int idx = it * 512 + tid;
      int row = idx >> 3, c = (idx & 7) ^ (row & 7);
      GLL16(W + (size_t)(n0 + row) * K + k0 + c * 8, Bs + it * 4096 + wbase);
    }
  };

  f32x4 acc[8][2] = {};
  const int NKT = K >> 6;

  stage(0, 0);
  stage(1, 1);

  int q = 0;
  for (int t = 0; t < NKT; ++t) {
    if (t + 2 < NKT) {
      int qn = q + 2; if (qn >= 3) qn -= 3;
      stage(qn, t + 2);
      asm volatile("s_waitcnt vmcnt(12)" ::: "memory");
    } else if (t + 1 < NKT) {
      asm volatile("s_waitcnt vmcnt(6)" ::: "memory");
    } else {
      asm volatile("s_waitcnt vmcnt(0)" ::: "memory");
    }
    __builtin_amdgcn_s_barrier();   // tile t fully in LDS for all waves

    const bf16_t* a_ = S + q * 24576;
    const bf16_t* b_ = a_ + 16384;
#pragma unroll
    for (int kk = 0; kk < 2; ++kk) {
      bf16x8 af[8], bw[2];
#pragma unroll
      for (int m = 0; m < 8; ++m) {
        int row = wr * 128 + m * 16 + r;
        af[m] = *(const bf16x8*)(a_ + row * 64 + (((kk * 4 + g) ^ (row & 7)) << 3));
      }
#pragma unroll
      for (int n = 0; n < 2; ++n) {
        int row = wc * 32 + n * 16 + r;
        bw[n] = *(const bf16x8*)(b_ + row * 64 + (((kk * 4 + g) ^ (row & 7)) << 3));
      }
#pragma unroll
      for (int m = 0; m < 8; ++m)
#pragma unroll
        for (int n = 0; n < 2; ++n)
          acc[m][n] = __builtin_amdgcn_mfma_f32_16x16x32_bf16(af[m], bw[n], acc[m][n], 0, 0, 0);
    }
    asm volatile("s_waitcnt lgkmcnt(0)" ::: "memory");
    __builtin_amdgcn_s_barrier();   // readers done before t+1 re-stages buf q
    ++q; if (q >= 3) q -= 3;
  }

#pragma unroll
  for (int n = 0; n < 2; ++n) {
    int col = n0 + wc * 32 + n * 16 + r;
    float bv = bias[col];
#pragma unroll
    for (int m = 0; m < 8; ++m) {
      int row0 = m0 + wr * 128 + m * 16 + g * 4;
#pragma unroll
      for (int j = 0; j < 4; ++j) {
        float vv = acc[m][n][j] + bv;
        if (OUT_F32)
          ((float*)Cout)[(size_t)(row0 + j) * N + col] = vv;
        else
          ((bf16_t*)Cout)[(size_t)(row0 + j) * N + col] = (bf16_t)vv;
      }
    }
  }
}

// O-projection: grid 256 = exactly 1 round at 1 block/CU; XCD-grouped.
__global__ __launch_bounds__(512, 2) void gemm_bt(const bf16_t* __restrict__ A,
                                                  const bf16_t* __restrict__ W,
                                                  const float* __restrict__ bias,
                                                  float* __restrict__ Cout,
                                                  int M, int N, int K) {
  __shared__ bf16_t S[3 * 24576];
  const int o = blockIdx.x;
  const int xcd = o & 7, s = o >> 3;   // s in [0,32)
  const int bx = s & 7, u = s >> 3;    // u in [0,4)
  const int by = xcd + 8 * u;          // all bx of one by share an XCD
  gemm_body<true>(S, A, W, bias, (void*)Cout, M, N, K, bx, by);
}

// QKV: grid 768 = exactly 3 rounds at 1 block/CU. Per XCD: 12 (z,by) panels
// x 8 bx — A-panel fetched once per XCD, W stays L2-resident.
__global__ __launch_bounds__(512, 2) void gemm_qkv(
    const bf16_t* A0, const bf16_t* W0, const float* b0, bf16_t* C0,
    const bf16_t* A1, const bf16_t* W1, const float* b1, bf16_t* C1,
    const bf16_t* A2, const bf16_t* W2, const float* b2, bf16_t* C2,
    int M, int N, int K) {
  __shared__ bf16_t S[3 * 24576];
  const int o = blockIdx.x;
  const int xcd = o & 7, s = o >> 3;   // s in [0,96)
  const int bx = s & 7, u = s >> 3;    // u in [0,12)
  const int zby = xcd + 8 * u;         // 0..95
  const int z = zby >> 5, by = zby & 31;
  const bf16_t* A = z == 0 ? A0 : z == 1 ? A1 : A2;
  const bf16_t* W = z == 0 ? W0 : z == 1 ? W1 : W2;
  const float* bb = z == 0 ? b0 : z == 1 ? b1 : b2;
  bf16_t* C = z == 0 ? C0 : z == 1 ? C1 : C2;
  gemm_body<false>(S, A, W, bb, (void*)C, M, N, K, bx, by);
}

// ---------------- causal flash attention (2-phase pipelined) ----------------
__global__ __launch_bounds__(256, 4) void attn_kernel(const bf16_t* __restrict__ Q1,
                                                      const bf16_t* __restrict__ K1,
                                                      const bf16_t* __restrict__ V1,
                                                      bf16_t* __restrict__ attn) {
  __shared__ bf16_t Kt[2][64 * 64];
  __shared__ bf16_t Vt[2][64 * 64];
  __shared__ bf16_t Pl[4][16 * 64];

  const int tid = threadIdx.x;
  const int l = tid & 63, w = tid >> 6;
  const int g = l >> 4, r = l & 15;

  // bijective XCD swizzle (nwg=1024): all blocks of a given (b,h) on one XCD.
  const int o = blockIdx.x;
  const int os = (o & 7) * 128 + (o >> 3);
  const int pair = os & 7, hb = os >> 3;
  const int h = hb & 15, b = hb >> 4;

  for (int ph = 0; ph < 2; ++ph) {
    const int qt = ph ? (NT - 1 - pair) : pair;

    const int qa = qt * 64 + w * 16 + r;
    const bf16_t* qptr = Q1 + ((size_t)b * NS + qa) * ND + h * 64;
    bf16x8 qf0 = *(const bf16x8*)(qptr + g * 8);
    bf16x8 qf1 = *(const bf16x8*)(qptr + 32 + g * 8);

    float mrun[4], lrun[4];
    f32x4 oacc[4] = {};
#pragma unroll
    for (int j = 0; j < 4; ++j) { mrun[j] = -1e30f; lrun[j] = 0.f; }
    const int qrow_base = qt * 64 + w * 16 + g * 4;

    __syncthreads();  // prior phase's readers done before we restage buffers

    // prologue: stage tile 0 into buffer 0
    bf16x8 vr0, vr1;
    {
#pragma unroll
      for (int it = 0; it < 2; ++it) {
        int idx = it * 256 + tid;
        int key = idx >> 3;
        int dkg = ((idx & 7) ^ (key & 7)) << 3;
        GLL16(K1 + ((size_t)b * NS + key) * ND + h * 64 + dkg,
              &Kt[0][(it * 256 + w * 64) * 8]);
      }
      vr0 = *(const bf16x8*)(V1 + ((size_t)b * NS + l) * ND + h * 64 + w * 8);
      vr1 = *(const bf16x8*)(V1 + ((size_t)b * NS + l) * ND + h * 64 + (4 + w) * 8);
    }

    for (int kt = 0; kt <= qt; ++kt) {
      const int p = kt & 1;
      const int k0 = kt * 64;

      // commit V regs -> Vt[p] (transposed + swizzled)
#pragma unroll
      for (int it = 0; it < 2; ++it) {
        int dkb = (it * 4 + w) * 8;
#pragma unroll
        for (int jj = 0; jj < 8; ++jj) {
          int dk = dkb + jj;
          int boff = dk * 128 + ((l * 2) ^ ((dk & 7) << 4));
          *(bf16_t*)((char*)Vt[p] + boff) = (it ? vr1 : vr0)[jj];
        }
      }
      __syncthreads();  // tile kt fully staged & visible

      // prefetch tile kt+1 into buffers p^1 (lands during compute below)
      if (kt < qt) {
        const int k0n = k0 + 64;
#pragma unroll
        for (int it = 0; it < 2; ++it) {
          int idx = it * 256 + tid;
          int key = idx >> 3;
          int dkg = ((idx & 7) ^ (key & 7)) << 3;
          GLL16(K1 + ((size_t)b * NS + k0n + key) * ND + h * 64 + dkg,
                &Kt[p ^ 1][(it * 256 + w * 64) * 8]);
        }
        vr0 = *(const bf16x8*)(V1 + ((size_t)b * NS + k0n + l) * ND + h * 64 + w * 8);
        vr1 = *(const bf16x8*)(V1 + ((size_t)b * NS + k0n + l) * ND + h * 64 + (4 + w) * 8);
      }

      // --- QK^T: 16x64 scores per wave
      f32x4 sacc[4] = {};
      __builtin_amdgcn_s_setprio(1);
#pragma unroll
      for (int n = 0; n < 4; ++n) {
        int key = n * 16 + r;
#pragma unroll
        for (int kk = 0; kk < 2; ++kk) {
          int dk2 = kk * 32 + g * 8;
          int boff = key * 128 + ((dk2 * 2) ^ ((key & 7) << 4));
          bf16x8 kf = *(const bf16x8*)((char*)Kt[p] + boff);
          sacc[n] = __builtin_amdgcn_mfma_f32_16x16x32_bf16(kk == 0 ? qf0 : qf1, kf, sacc[n], 0, 0, 0);
        }
      }
      __builtin_amdgcn_s_setprio(0);

      // --- online softmax (C-layout: row = g*4+j, col = n*16+r)
      const bool diag = (kt == qt);
      float m_new[4], esc[4];
#pragma unroll
      for (int j = 0; j < 4; ++j) {
        float mx = -1e30f;
#pragma unroll
        for (int n = 0; n < 4; ++n) {
          float s = sacc[n][j] * 0.125f;
          if (diag && (k0 + n * 16 + r) > (qrow_base + j)) s = -1e30f;
          sacc[n][j] = s;
          mx = fmaxf(mx, s);
        }
        mx = fmaxf(mx, __shfl_xor(mx, 1));
        mx = fmaxf(mx, __shfl_xor(mx, 2));
        mx = fmaxf(mx, __shfl_xor(mx, 4));
        mx = fmaxf(mx, __shfl_xor(mx, 8));
        m_new[j] = fmaxf(mrun[j], mx);
        esc[j] = __expf(mrun[j] - m_new[j]);
        mrun[j] = m_new[j];
      }
      float rsum[4] = {0.f, 0.f, 0.f, 0.f};
#pragma unroll
      for (int n = 0; n < 4; ++n)
#pragma unroll
        for (int j = 0; j < 4; ++j) {
          float pe = __expf(sacc[n][j] - m_new[j]);
          rsum[j] += pe;
          int row = g * 4 + j, col = n * 16 + r;
          int boff = row * 128 + ((col * 2) ^ ((row & 7) << 4));
          *(bf16_t*)((char*)Pl[w] + boff) = (bf16_t)pe;
        }
#pragma unroll
      for (int j = 0; j < 4; ++j) {
        float s2 = rsum[j];
        s2 += __shfl_xor(s2, 1); s2 += __shfl_xor(s2, 2);
        s2 += __shfl_xor(s2, 4); s2 += __shfl_xor(s2, 8);
        lrun[j] = lrun[j] * esc[j] + s2;
      }
#pragma unroll
      for (int n = 0; n < 4; ++n)
#pragma unroll
        for (int j = 0; j < 4; ++j) oacc[n][j] *= esc[j];

      // --- PV: P (16x64) x V (64x64)
      __builtin_amdgcn_s_setprio(1);
#pragma unroll
      for (int kk = 0; kk < 2; ++kk) {
        int keyb = kk * 32 + g * 8;
        int poff = r * 128 + ((keyb * 2) ^ ((r & 7) << 4));
        bf16x8 pf = *(const bf16x8*)((char*)Pl[w] + poff);
#pragma unroll
        for (int n = 0; n < 4; ++n) {
          int dk2 = n * 16 + r;
          int voff = dk2 * 128 + ((keyb * 2) ^ ((dk2 & 7) << 4));
          bf16x8 vf = *(const bf16x8*)((char*)Vt[p] + voff);
          oacc[n] = __builtin_amdgcn_mfma_f32_16x16x32_bf16(pf, vf, oacc[n], 0, 0, 0);
        }
      }
      __builtin_amdgcn_s_setprio(0);
    }  // kt

    // epilogue: O /= l, write bf16
#pragma unroll
    for (int n = 0; n < 4; ++n) {
      int dk2 = n * 16 + r;
#pragma unroll
      for (int j = 0; j < 4; ++j) {
        float ov = oacc[n][j] / lrun[j];
        attn[((size_t)b * NS + qrow_base + j) * ND + h * 64 + dk2] = (bf16_t)ov;
      }
    }
  }  // ph
}

// ---------------- launch ----------------
extern "C" void kernel_launch(void* const* d_in, const int* in_sizes, int n_in,
                              void* d_out, int out_size, void* d_ws, size_t ws_size,
                              hipStream_t stream) {
  const float* q  = (const float*)d_in[0];
  const float* k  = (const float*)d_in[1];
  const float* v  = (const float*)d_in[2];
  // d_in[3] = mask (int32 tril, implemented analytically)
  const float* Wq = (const float*)d_in[4];
  const float* bq = (const float*)d_in[5];
  const float* Wk = (const float*)d_in[6];
  const float* bk = (const float*)d_in[7];
  const float* Wv = (const float*)d_in[8];
  const float* bv = (const float*)d_in[9];
  const float* Wo = (const float*)d_in[10];
  const float* bo = (const float*)d_in[11];
  float* out = (float*)d_out;

  const size_t NX = (size_t)NB * NS * ND;  // 8388608
  const size_t NW = (size_t)ND * ND;       // 1048576
  char* ws = (char*)d_ws;
  size_t off = 0;
  auto alloc = [&](size_t bytes) {
    char* p = ws + off;
    off += (bytes + 255) & ~(size_t)255;
    return p;
  };
  bf16_t* xq  = (bf16_t*)alloc(NX * 2);
  bf16_t* xk  = (bf16_t*)alloc(NX * 2);
  bf16_t* xv  = (bf16_t*)alloc(NX * 2);
  bf16_t* wqb = (bf16_t*)alloc(NW * 2);
  bf16_t* wkb = (bf16_t*)alloc(NW * 2);
  bf16_t* wvb = (bf16_t*)alloc(NW * 2);
  bf16_t* wob = (bf16_t*)alloc(NW * 2);
  bf16_t* q1  = (bf16_t*)alloc(NX * 2);
  bf16_t* k1  = (bf16_t*)alloc(NX * 2);
  bf16_t* v1  = (bf16_t*)alloc(NX * 2);
  bf16_t* at  = xq;  // xq dead after QKV GEMMs; reuse for attn output

  dim3 blk(256);
  cvt3_kernel<<<dim3(1024, 3), blk, 0, stream>>>(q, xq, k, xk, v, xv, (long)NX);
  cvt4_kernel<<<dim3(128, 4), blk, 0, stream>>>(Wq, wqb, Wk, wkb, Wv, wvb, Wo, wob, (long)NW);

  gemm_qkv<<<dim3(768), dim3(512), 0, stream>>>(
      xq, wqb, bq, q1, xk, wkb, bk, k1, xv, wvb, bv, v1, NB * NS, ND, ND);

  attn_kernel<<<dim3((NT / 2) * NH * NB), blk, 0, stream>>>(q1, k1, v1, at);

  gemm_bt<<<dim3(256), dim3(512), 0, stream>>>(at, wob, bo, out, NB * NS, ND, ND);
}

// Round 5
// 157.029 us; speedup vs baseline: 1.9687x; 1.1569x over previous
//
#include <hip/hip_runtime.h>
#include <hip/hip_bf16.h>
#include <stdint.h>

// Problem constants
constexpr int NB = 8;     // batch
constexpr int NS = 1024;  // seq
constexpr int ND = 1024;  // model dim
constexpr int NH = 16;    // heads
constexpr int NDK = 64;   // head dim
constexpr int NT = NS / 64;  // 16 q-tiles of 64 rows

typedef __bf16 bf16_t;
typedef __attribute__((ext_vector_type(8))) __bf16 bf16x8;
typedef __attribute__((ext_vector_type(4))) __bf16 bf16x4;
typedef __attribute__((ext_vector_type(4))) float f32x4;

#define GLL16(g, s) __builtin_amdgcn_global_load_lds( \
    (const __attribute__((address_space(1))) void*)(g), \
    (__attribute__((address_space(3))) void*)(s), 16, 0, 0)

// ---------------- fp32 -> bf16 converts (fused launches) ----------------
__device__ __forceinline__ void cvt_body(const float* __restrict__ s,
                                         bf16_t* __restrict__ d, long n) {
  long i0 = (long)(blockIdx.x * blockDim.x + threadIdx.x) * 4;
  long step = (long)gridDim.x * blockDim.x * 4;
  for (long i = i0; i < n; i += step) {
    float4 f = *(const float4*)(s + i);
    bf16x4 o;
    o[0] = (bf16_t)f.x; o[1] = (bf16_t)f.y; o[2] = (bf16_t)f.z; o[3] = (bf16_t)f.w;
    *(bf16x4*)(d + i) = o;
  }
}

__global__ __launch_bounds__(256) void cvt3_kernel(const float* s0, bf16_t* d0,
                                                   const float* s1, bf16_t* d1,
                                                   const float* s2, bf16_t* d2, long n) {
  const float* s = blockIdx.y == 0 ? s0 : blockIdx.y == 1 ? s1 : s2;
  bf16_t* d = blockIdx.y == 0 ? d0 : blockIdx.y == 1 ? d1 : d2;
  cvt_body(s, d, n);
}

__global__ __launch_bounds__(256) void cvt4_kernel(const float* s0, bf16_t* d0,
                                                   const float* s1, bf16_t* d1,
                                                   const float* s2, bf16_t* d2,
                                                   const float* s3, bf16_t* d3, long n) {
  const float* s = blockIdx.y == 0 ? s0 : blockIdx.y == 1 ? s1 : blockIdx.y == 2 ? s2 : s3;
  bf16_t* d = blockIdx.y == 0 ? d0 : blockIdx.y == 1 ? d1 : blockIdx.y == 2 ? d2 : d3;
  cvt_body(s, d, n);
}

// ---------------- GEMM: C[M,N] = A[M,K] @ W[N,K]^T + bias ----------------
// 256x128 tile, 8 waves (2M x 4N, per-wave 128x32), BK=64, mfma 16x16x32.
// Triple-buffered LDS (144 KB, 1 block/CU), prefetch distance 2, counted
// vmcnt (T4). Raw s_barrier. XOR-swizzled LDS rows (128 B) with pre-swizzled
// global_load_lds source. 0 bank conflicts, ~ideal FETCH (verified R3/R4).
template<bool OUT_F32>
__device__ __forceinline__ void gemm_body(bf16_t* S,
                                          const bf16_t* __restrict__ A,
                                          const bf16_t* __restrict__ W,
                                          const float* __restrict__ bias,
                                          void* __restrict__ Cout,
                                          int M, int N, int K, int bx, int by) {
  const int tid = threadIdx.x;           // 0..511
  const int l = tid & 63, w = tid >> 6;  // 8 waves
  const int wr = w >> 2, wc = w & 3;
  const int g = l >> 4, r = l & 15;
  const int m0 = by * 256, n0 = bx * 128;
  const int wbase = (tid & 448) * 8;     // wave-uniform LDS base

  auto stage = [&](int q, int t) {
    const int k0 = t << 6;
    bf16_t* As = S + q * 24576;
    bf16_t* Bs = As + 16384;
#pragma unroll
    for (int it = 0; it < 4; ++it) {       // A: 256 rows x 8 chunks
      int idx = it * 512 + tid;
      int row = idx >> 3, c = (idx & 7) ^ (row & 7);
      GLL16(A + (size_t)(m0 + row) * K + k0 + c * 8, As + it * 4096 + wbase);
    }
#pragma unroll
    for (int it = 0; it < 2; ++it) {       // B: 128 rows x 8 chunks
      int idx = it * 512 + tid;
      int row = idx >> 3, c = (idx & 7) ^ (row & 7);
      GLL16(W + (size_t)(n0 + row) * K + k0 + c * 8, Bs + it * 4096 + wbase);
    }
  };

  f32x4 acc[8][2] = {};
  const int NKT = K >> 6;

  stage(0, 0);
  stage(1, 1);

  int q = 0;
  for (int t = 0; t < NKT; ++t) {
    if (t + 2 < NKT) {
      int qn = q + 2; if (qn >= 3) qn -= 3;
      stage(qn, t + 2);
      asm volatile("s_waitcnt vmcnt(12)" ::: "memory");
    } else if (t + 1 < NKT) {
      asm volatile("s_waitcnt vmcnt(6)" ::: "memory");
    } else {
      asm volatile("s_waitcnt vmcnt(0)" ::: "memory");
    }
    __builtin_amdgcn_s_barrier();   // tile t fully in LDS for all waves

    const bf16_t* a_ = S + q * 24576;
    const bf16_t* b_ = a_ + 16384;
#pragma unroll
    for (int kk = 0; kk < 2; ++kk) {
      bf16x8 af[8], bw[2];
#pragma unroll
      for (int m = 0; m < 8; ++m) {
        int row = wr * 128 + m * 16 + r;
        af[m] = *(const bf16x8*)(a_ + row * 64 + (((kk * 4 + g) ^ (row & 7)) << 3));
      }
#pragma unroll
      for (int n = 0; n < 2; ++n) {
        int row = wc * 32 + n * 16 + r;
        bw[n] = *(const bf16x8*)(b_ + row * 64 + (((kk * 4 + g) ^ (row & 7)) << 3));
      }
#pragma unroll
      for (int m = 0; m < 8; ++m)
#pragma unroll
        for (int n = 0; n < 2; ++n)
          acc[m][n] = __builtin_amdgcn_mfma_f32_16x16x32_bf16(af[m], bw[n], acc[m][n], 0, 0, 0);
    }
    asm volatile("s_waitcnt lgkmcnt(0)" ::: "memory");
    __builtin_amdgcn_s_barrier();   // readers done before t+1 re-stages buf q
    ++q; if (q >= 3) q -= 3;
  }

#pragma unroll
  for (int n = 0; n < 2; ++n) {
    int col = n0 + wc * 32 + n * 16 + r;
    float bv = bias[col];
#pragma unroll
    for (int m = 0; m < 8; ++m) {
      int row0 = m0 + wr * 128 + m * 16 + g * 4;
#pragma unroll
      for (int j = 0; j < 4; ++j) {
        float vv = acc[m][n][j] + bv;
        if (OUT_F32)
          ((float*)Cout)[(size_t)(row0 + j) * N + col] = vv;
        else
          ((bf16_t*)Cout)[(size_t)(row0 + j) * N + col] = (bf16_t)vv;
      }
    }
  }
}

// O-projection: grid 256 = exactly 1 round at 1 block/CU; XCD-grouped.
__global__ __launch_bounds__(512, 2) void gemm_bt(const bf16_t* __restrict__ A,
                                                  const bf16_t* __restrict__ W,
                                                  const float* __restrict__ bias,
                                                  float* __restrict__ Cout,
                                                  int M, int N, int K) {
  __shared__ bf16_t S[3 * 24576];
  const int o = blockIdx.x;
  const int xcd = o & 7, s = o >> 3;   // s in [0,32)
  const int bx = s & 7, u = s >> 3;    // u in [0,4)
  const int by = xcd + 8 * u;          // all bx of one by share an XCD
  gemm_body<true>(S, A, W, bias, (void*)Cout, M, N, K, bx, by);
}

// QKV: grid 768 = exactly 3 rounds at 1 block/CU; XCD-grouped.
__global__ __launch_bounds__(512, 2) void gemm_qkv(
    const bf16_t* A0, const bf16_t* W0, const float* b0, bf16_t* C0,
    const bf16_t* A1, const bf16_t* W1, const float* b1, bf16_t* C1,
    const bf16_t* A2, const bf16_t* W2, const float* b2, bf16_t* C2,
    int M, int N, int K) {
  __shared__ bf16_t S[3 * 24576];
  const int o = blockIdx.x;
  const int xcd = o & 7, s = o >> 3;   // s in [0,96)
  const int bx = s & 7, u = s >> 3;    // u in [0,12)
  const int zby = xcd + 8 * u;         // 0..95
  const int z = zby >> 5, by = zby & 31;
  const bf16_t* A = z == 0 ? A0 : z == 1 ? A1 : A2;
  const bf16_t* W = z == 0 ? W0 : z == 1 ? W1 : W2;
  const float* bb = z == 0 ? b0 : z == 1 ? b1 : b2;
  bf16_t* C = z == 0 ? C0 : z == 1 ? C1 : C2;
  gemm_body<false>(S, A, W, bb, (void*)C, M, N, K, bx, by);
}

// ---------------- causal flash attention (2-phase, swapped QK^T) ----------
// Swapped-operand QK^T: sacc = mfma(K, Q) = S^T, so lane (g,r) holds 16
// scores of ITS OWN q-row r (keys 16n+4g+j). Row softmax = in-register
// reduce + 2 shuffles (xor16/32); m,l are per-lane scalars. P stored as
// Pl[q][key] via 4x ds_write_b64. PV computed as O^T = V^T P^T (mfma(vf,pf))
// so the esc rescale and l-divide are lane-local. Scale 0.125*log2e folded
// into Q; exp2 direct; T13 defer-max (THR=8, log2 domain).
__global__ __launch_bounds__(256, 4) void attn_kernel(const bf16_t* __restrict__ Q1,
                                                      const bf16_t* __restrict__ K1,
                                                      const bf16_t* __restrict__ V1,
                                                      bf16_t* __restrict__ attn) {
  __shared__ bf16_t Kt[2][64 * 64];
  __shared__ bf16_t Vt[2][64 * 64];
  __shared__ bf16_t Pl[4][16 * 64];

  const int tid = threadIdx.x;
  const int l = tid & 63, w = tid >> 6;
  const int g = l >> 4, r = l & 15;

  // bijective XCD swizzle (nwg=1024): all blocks of a given (b,h) on one XCD.
  const int o = blockIdx.x;
  const int os = (o & 7) * 128 + (o >> 3);
  const int pair = os & 7, hb = os >> 3;
  const int h = hb & 15, b = hb >> 4;

  constexpr float SC = 0.18033688011112042f;  // 0.125 * log2(e)

  for (int ph = 0; ph < 2; ++ph) {
    const int qt = ph ? (NT - 1 - pair) : pair;
    const int qrow_g = qt * 64 + w * 16 + r;  // this lane's q-row (global)

    const bf16_t* qptr = Q1 + ((size_t)b * NS + qrow_g) * ND + h * 64;
    bf16x8 qf0 = *(const bf16x8*)(qptr + g * 8);
    bf16x8 qf1 = *(const bf16x8*)(qptr + 32 + g * 8);
#pragma unroll
    for (int i = 0; i < 8; ++i) {
      qf0[i] = (bf16_t)((float)qf0[i] * SC);
      qf1[i] = (bf16_t)((float)qf1[i] * SC);
    }

    float mrun = -1e30f, lrun = 0.f;
    f32x4 oacc[4] = {};

    __syncthreads();  // prior phase's readers done before we restage buffers

    // prologue: stage tile 0 into buffer 0
    bf16x8 vr0, vr1;
    {
#pragma unroll
      for (int it = 0; it < 2; ++it) {
        int idx = it * 256 + tid;
        int key = idx >> 3;
        int dkg = ((idx & 7) ^ (key & 7)) << 3;
        GLL16(K1 + ((size_t)b * NS + key) * ND + h * 64 + dkg,
              &Kt[0][(it * 256 + w * 64) * 8]);
      }
      vr0 = *(const bf16x8*)(V1 + ((size_t)b * NS + l) * ND + h * 64 + w * 8);
      vr1 = *(const bf16x8*)(V1 + ((size_t)b * NS + l) * ND + h * 64 + (4 + w) * 8);
    }

    for (int kt = 0; kt <= qt; ++kt) {
      const int p = kt & 1;
      const int k0 = kt * 64;

      // commit V regs -> Vt[p] (transposed + swizzled)
#pragma unroll
      for (int it = 0; it < 2; ++it) {
        int dkb = (it * 4 + w) * 8;
#pragma unroll
        for (int jj = 0; jj < 8; ++jj) {
          int dk = dkb + jj;
          int boff = dk * 128 + ((l * 2) ^ ((dk & 7) << 4));
          *(bf16_t*)((char*)Vt[p] + boff) = (it ? vr1 : vr0)[jj];
        }
      }
      __syncthreads();  // tile kt fully staged & visible

      // prefetch tile kt+1 into buffers p^1 (lands during compute below)
      if (kt < qt) {
        const int k0n = k0 + 64;
#pragma unroll
        for (int it = 0; it < 2; ++it) {
          int idx = it * 256 + tid;
          int key = idx >> 3;
          int dkg = ((idx & 7) ^ (key & 7)) << 3;
          GLL16(K1 + ((size_t)b * NS + k0n + key) * ND + h * 64 + dkg,
                &Kt[p ^ 1][(it * 256 + w * 64) * 8]);
        }
        vr0 = *(const bf16x8*)(V1 + ((size_t)b * NS + k0n + l) * ND + h * 64 + w * 8);
        vr1 = *(const bf16x8*)(V1 + ((size_t)b * NS + k0n + l) * ND + h * 64 + (4 + w) * 8);
      }

      // --- QK^T (swapped): sacc[n] rows = keys 16n+4g+j, col = q-row r
      f32x4 sacc[4] = {};
      __builtin_amdgcn_s_setprio(1);
#pragma unroll
      for (int n = 0; n < 4; ++n) {
        int key = n * 16 + r;
#pragma unroll
        for (int kk = 0; kk < 2; ++kk) {
          int dk2 = kk * 32 + g * 8;
          int boff = key * 128 + ((dk2 * 2) ^ ((key & 7) << 4));
          bf16x8 kf = *(const bf16x8*)((char*)Kt[p] + boff);
          sacc[n] = __builtin_amdgcn_mfma_f32_16x16x32_bf16(kf, kk == 0 ? qf0 : qf1, sacc[n], 0, 0, 0);
        }
      }
      __builtin_amdgcn_s_setprio(0);

      // --- causal mask (diag tile only): key = k0+16n+4g+j vs qrow_g
      if (kt == qt) {
#pragma unroll
        for (int n = 0; n < 4; ++n)
#pragma unroll
          for (int j = 0; j < 4; ++j)
            if (k0 + n * 16 + g * 4 + j > qrow_g) sacc[n][j] = -1e30f;
      }

      // --- per-lane max over 16, then 2 cross-lane shuffles
      float mx;
      {
        float t0 = fmaxf(fmaxf(sacc[0][0], sacc[0][1]), fmaxf(sacc[0][2], sacc[0][3]));
        float t1 = fmaxf(fmaxf(sacc[1][0], sacc[1][1]), fmaxf(sacc[1][2], sacc[1][3]));
        float t2 = fmaxf(fmaxf(sacc[2][0], sacc[2][1]), fmaxf(sacc[2][2], sacc[2][3]));
        float t3 = fmaxf(fmaxf(sacc[3][0], sacc[3][1]), fmaxf(sacc[3][2], sacc[3][3]));
        mx = fmaxf(fmaxf(t0, t1), fmaxf(t2, t3));
      }
      mx = fmaxf(mx, __shfl_xor(mx, 16));
      mx = fmaxf(mx, __shfl_xor(mx, 32));

      // --- T13 defer-max: only rescale when max grew past THR (log2 units)
      if (!__all(mx <= mrun + 8.0f)) {
        float m_new = fmaxf(mrun, mx);
        float esc = __builtin_amdgcn_exp2f(mrun - m_new);
        mrun = m_new;
        lrun *= esc;
#pragma unroll
        for (int n = 0; n < 4; ++n)
#pragma unroll
          for (int j = 0; j < 4; ++j) oacc[n][j] *= esc;
      }

      // --- P = exp2(S - m), store P[q=r][key] (4x ds_write_b64), row-sum
      float rsum = 0.f;
#pragma unroll
      for (int n = 0; n < 4; ++n) {
        bf16x4 p4;
#pragma unroll
        for (int j = 0; j < 4; ++j) {
          float pe = __builtin_amdgcn_exp2f(sacc[n][j] - mrun);
          rsum += pe;
          p4[j] = (bf16_t)pe;
        }
        *(bf16x4*)((char*)Pl[w] + r * 128 + ((n * 32 + g * 8) ^ ((r & 7) << 4))) = p4;
      }
      rsum += __shfl_xor(rsum, 16);
      rsum += __shfl_xor(rsum, 32);
      lrun += rsum;

      // --- PV: O^T = V^T P^T; lane-local rescale/divide
      __builtin_amdgcn_s_setprio(1);
#pragma unroll
      for (int kk = 0; kk < 2; ++kk) {
        bf16x8 pf = *(const bf16x8*)((char*)Pl[w] + r * 128 + ((kk * 64 + g * 16) ^ ((r & 7) << 4)));
#pragma unroll
        for (int n = 0; n < 4; ++n) {
          int dkr = n * 16 + r;
          bf16x8 vf = *(const bf16x8*)((char*)Vt[p] + dkr * 128 + ((kk * 64 + g * 16) ^ ((r & 7) << 4)));
          oacc[n] = __builtin_amdgcn_mfma_f32_16x16x32_bf16(vf, pf, oacc[n], 0, 0, 0);
        }
      }
      __builtin_amdgcn_s_setprio(0);
    }  // kt

    // epilogue: O[q=r][dk=16n+4g+j] /= l; 4x 8B stores
    float linv = 1.0f / lrun;
#pragma unroll
    for (int n = 0; n < 4; ++n) {
      bf16x4 o4;
#pragma unroll
      for (int j = 0; j < 4; ++j) o4[j] = (bf16_t)(oacc[n][j] * linv);
      *(bf16x4*)(attn + ((size_t)b * NS + qrow_g) * ND + h * 64 + n * 16 + g * 4) = o4;
    }
  }  // ph
}

// ---------------- launch ----------------
extern "C" void kernel_launch(void* const* d_in, const int* in_sizes, int n_in,
                              void* d_out, int out_size, void* d_ws, size_t ws_size,
                              hipStream_t stream) {
  const float* q  = (const float*)d_in[0];
  const float* k  = (const float*)d_in[1];
  const float* v  = (const float*)d_in[2];
  // d_in[3] = mask (int32 tril, implemented analytically)
  const float* Wq = (const float*)d_in[4];
  const float* bq = (const float*)d_in[5];
  const float* Wk = (const float*)d_in[6];
  const float* bk = (const float*)d_in[7];
  const float* Wv = (const float*)d_in[8];
  const float* bv = (const float*)d_in[9];
  const float* Wo = (const float*)d_in[10];
  const float* bo = (const float*)d_in[11];
  float* out = (float*)d_out;

  const size_t NX = (size_t)NB * NS * ND;  // 8388608
  const size_t NW = (size_t)ND * ND;       // 1048576
  char* ws = (char*)d_ws;
  size_t off = 0;
  auto alloc = [&](size_t bytes) {
    char* p = ws + off;
    off += (bytes + 255) & ~(size_t)255;
    return p;
  };
  bf16_t* xq  = (bf16_t*)alloc(NX * 2);
  bf16_t* xk  = (bf16_t*)alloc(NX * 2);
  bf16_t* xv  = (bf16_t*)alloc(NX * 2);
  bf16_t* wqb = (bf16_t*)alloc(NW * 2);
  bf16_t* wkb = (bf16_t*)alloc(NW * 2);
  bf16_t* wvb = (bf16_t*)alloc(NW * 2);
  bf16_t* wob = (bf16_t*)alloc(NW * 2);
  bf16_t* q1  = (bf16_t*)alloc(NX * 2);
  bf16_t* k1  = (bf16_t*)alloc(NX * 2);
  bf16_t* v1  = (bf16_t*)alloc(NX * 2);
  bf16_t* at  = xq;  // xq dead after QKV GEMMs; reuse for attn output

  dim3 blk(256);
  cvt3_kernel<<<dim3(1024, 3), blk, 0, stream>>>(q, xq, k, xk, v, xv, (long)NX);
  cvt4_kernel<<<dim3(128, 4), blk, 0, stream>>>(Wq, wqb, Wk, wkb, Wv, wvb, Wo, wob, (long)NW);

  gemm_qkv<<<dim3(768), dim3(512), 0, stream>>>(
      xq, wqb, bq, q1, xk, wkb, bk, k1, xv, wvb, bv, v1, NB * NS, ND, ND);

  attn_kernel<<<dim3((NT / 2) * NH * NB), blk, 0, stream>>>(q1, k1, v1, at);

  gemm_bt<<<dim3(256), dim3(512), 0, stream>>>(at, wob, bo, out, NB * NS, ND, ND);
}